// Round 15
// baseline (251.597 us; speedup 1.0000x reference)
//
#include <hip/hip_runtime.h>

typedef unsigned short u16;
typedef __bf16 bf16;
typedef bf16 bf16x8 __attribute__((ext_vector_type(8)));
typedef float f32x4 __attribute__((ext_vector_type(4)));

// ---------------- helpers ----------------

__device__ __forceinline__ u16 f2bf(float f) {
  bf16 b = (bf16)f;
  return __builtin_bit_cast(u16, b);
}

__device__ __forceinline__ float b2f(u16 u) {
  return __uint_as_float(((unsigned)u) << 16);
}

__device__ __forceinline__ float fexp2(float x) {
#if __has_builtin(__builtin_amdgcn_exp2f)
  return __builtin_amdgcn_exp2f(x);
#else
  return exp2f(x);
#endif
}

__device__ __forceinline__ void gll16(void* lds, const void* g) {
  __builtin_amdgcn_global_load_lds((__attribute__((address_space(1))) void*)g,
                                   (__attribute__((address_space(3))) void*)lds,
                                   16, 0, 0);
}

__device__ __forceinline__ f32x4 mfma16(bf16x8 a, bf16x8 b, f32x4 c) {
  return __builtin_amdgcn_mfma_f32_16x16x32_bf16(a, b, c, 0, 0, 0);
}

// ---------------- all weight transposes fused: fp32 [R][C] -> bf16 [C][R] ----

__global__ __launch_bounds__(256)
void transpose_all(const float* __restrict__ Wq, const float* __restrict__ Wk,
                   const float* __restrict__ Wv, const float* __restrict__ Wo,
                   const float* __restrict__ W1, const float* __restrict__ W2,
                   u16* __restrict__ WqT, u16* __restrict__ WkT,
                   u16* __restrict__ WvT, u16* __restrict__ WoT,
                   u16* __restrict__ W1T, u16* __restrict__ W2T) {
  __shared__ float tile[32][33];
  const int id = blockIdx.x;
  const float* src;
  u16* dst;
  int R, C, t;
  if (id < 4096) {
    const int w = id >> 10;
    t = id & 1023; R = 1024; C = 1024;
    src = w == 0 ? Wq : w == 1 ? Wk : w == 2 ? Wv : Wo;
    dst = w == 0 ? WqT : w == 1 ? WkT : w == 2 ? WvT : WoT;
  } else if (id < 8192) {
    t = id - 4096; R = 1024; C = 4096; src = W1; dst = W1T;
  } else {
    t = id - 8192; R = 4096; C = 1024; src = W2; dst = W2T;
  }
  const int tilesx = C >> 5;
  const int c0 = (t % tilesx) * 32, r0 = (t / tilesx) * 32;
  const int tx = threadIdx.x, ty = threadIdx.y;   // 32 x 8
#pragma unroll
  for (int i = 0; i < 4; ++i)
    tile[ty + i * 8][tx] = src[(size_t)(r0 + ty + i * 8) * C + c0 + tx];
  __syncthreads();
#pragma unroll
  for (int i = 0; i < 4; ++i)
    dst[(size_t)(c0 + ty + i * 8) * R + r0 + tx] = f2bf(tile[tx][ty + i * 8]);
}

// ---------------- layernorm: row -> bf16 row (C=1024); input f32 or bf16 ----

template <int BF16IN>
__global__ __launch_bounds__(256)
void ln_kernel(const void* __restrict__ xin, const float* __restrict__ g,
               const float* __restrict__ bb, u16* __restrict__ h) {
  const int row = blockIdx.x;
  const int tid = threadIdx.x;
  float4 xv;
  if (BF16IN) {
    const ushort4 u = ((const ushort4*)((const u16*)xin + (size_t)row * 1024))[tid];
    xv.x = b2f(u.x); xv.y = b2f(u.y); xv.z = b2f(u.z); xv.w = b2f(u.w);
  } else {
    xv = ((const float4*)((const float*)xin + (size_t)row * 1024))[tid];
  }
  float s = xv.x + xv.y + xv.z + xv.w;
  float q = xv.x * xv.x + xv.y * xv.y + xv.z * xv.z + xv.w * xv.w;
#pragma unroll
  for (int m = 1; m < 64; m <<= 1) {
    s += __shfl_xor(s, m);
    q += __shfl_xor(q, m);
  }
  __shared__ float ss[4], qq[4];
  const int wid = tid >> 6, lane = tid & 63;
  if (lane == 0) { ss[wid] = s; qq[wid] = q; }
  __syncthreads();
  s = ss[0] + ss[1] + ss[2] + ss[3];
  q = qq[0] + qq[1] + qq[2] + qq[3];
  const float mean = s * (1.0f / 1024.0f);
  const float var = q * (1.0f / 1024.0f) - mean * mean;
  const float rs = rsqrtf(var + 1e-5f);
  const float4 gv = ((const float4*)g)[tid];
  const float4 bv = ((const float4*)bb)[tid];
  ushort4 o;
  o.x = f2bf((xv.x - mean) * rs * gv.x + bv.x);
  o.y = f2bf((xv.y - mean) * rs * gv.y + bv.y);
  o.z = f2bf((xv.z - mean) * rs * gv.z + bv.z);
  o.w = f2bf((xv.w - mean) * rs * gv.w + bv.w);
  ((ushort4*)(h + (size_t)row * 1024))[tid] = o;
}

// ---------------- XCD-aware block swizzle (bijective, nwg%8==0) -------------

__device__ __forceinline__ void xcd_swizzle(int& bx, int& by, int& bz) {
  const int gx = gridDim.x, gy = gridDim.y;
  const int nwg = gx * gy * (int)gridDim.z;
  int flat = (int)blockIdx.x + gx * ((int)blockIdx.y + gy * (int)blockIdx.z);
  flat = (flat & 7) * (nwg >> 3) + (flat >> 3);
  bx = flat % gx;
  const int rem = flat / gx;
  by = rem % gy;
  bz = rem / gy;
}

// ---------------- GEMM 256x128, 512 thr / 8 waves, BK=32, 3-buf -------------
// EPI 0: QKV fused (N=3072); col seg 0->q, 1->k, 2->vt [bh][d][t].
// EPI 1: out bf16 = relu(acc + bias).

template <int EPI>
__global__ __launch_bounds__(512)
void gemm256(const u16* __restrict__ A, const u16* __restrict__ Bt,
             const float* __restrict__ bias,
             void* __restrict__ O0, void* __restrict__ O1, void* __restrict__ O2,
             int M, int N, int K) {
  __shared__ __align__(16) u16 Alds[3][256 * 32];   // 16KB each
  __shared__ __align__(16) u16 Blds[3][128 * 32];   // 8KB each
  const int tid = threadIdx.x;
  const int lane = tid & 63, wid = tid >> 6;        // wid 0..7
  const int rl = lane & 15, kg = lane >> 4;
  const int ksw = (rl >> 1) & 3;
  int bx, by, bz;
  xcd_swizzle(bx, by, bz);
  const int m0 = by * 256, n0 = bx * 128;
  f32x4 acc[4][4];
#pragma unroll
  for (int i = 0; i < 4; ++i)
#pragma unroll
    for (int j = 0; j < 4; ++j) acc[i][j] = (f32x4){0.f, 0.f, 0.f, 0.f};
  const int wr = wid >> 1, wc = wid & 1;            // 4x2 wave grid
  const int srow = lane >> 2;                       // 0..15 within instr
  const int skol = (((lane & 3) ^ ((lane >> 3) & 3))) * 8;  // pre-swizzled

#define STAGE_256(buf, k0)                                                     \
  {                                                                            \
    gll16(Alds[buf] + (wid * 32 + 0) * 32,                                     \
          A + (size_t)(m0 + wid * 32 + 0 + srow) * K + (k0) + skol);           \
    gll16(Alds[buf] + (wid * 32 + 16) * 32,                                    \
          A + (size_t)(m0 + wid * 32 + 16 + srow) * K + (k0) + skol);          \
    gll16(Blds[buf] + (wid * 16) * 32,                                         \
          Bt + (size_t)(n0 + wid * 16 + srow) * K + (k0) + skol);              \
  }

  const int nt = K >> 5;
  STAGE_256(0, 0);
  STAGE_256(1, 32);
  int cur = 0;
  for (int t = 0; t < nt; ++t) {
    if (t + 1 < nt)
      asm volatile("s_waitcnt vmcnt(3)" ::: "memory");
    else
      asm volatile("s_waitcnt vmcnt(0)" ::: "memory");
    __builtin_amdgcn_s_barrier();
    if (t + 2 < nt) {
      const int nxt = cur >= 1 ? cur - 1 : cur + 2;   // (cur+2)%3
      STAGE_256(nxt, (t + 2) << 5);
    }
    bf16x8 af[4], bfr[4];
#pragma unroll
    for (int m = 0; m < 4; ++m)
      af[m] = *(const bf16x8*)(Alds[cur] + (wr * 64 + m * 16 + rl) * 32 +
                               (kg ^ ksw) * 8);
#pragma unroll
    for (int n = 0; n < 4; ++n)
      bfr[n] = *(const bf16x8*)(Blds[cur] + (wc * 64 + n * 16 + rl) * 32 +
                                (kg ^ ksw) * 8);
    __builtin_amdgcn_s_setprio(1);
#pragma unroll
    for (int m = 0; m < 4; ++m)
#pragma unroll
      for (int n = 0; n < 4; ++n)
        acc[m][n] = mfma16(af[m], bfr[n], acc[m][n]);
    __builtin_amdgcn_s_setprio(0);
    cur = cur + 1 == 3 ? 0 : cur + 1;
  }
#undef STAGE_256

#pragma unroll
  for (int m = 0; m < 4; ++m) {
#pragma unroll
    for (int n = 0; n < 4; ++n) {
      const int col = n0 + wc * 64 + n * 16 + rl;
      const int row0 = m0 + wr * 64 + m * 16 + kg * 4;
      if (EPI == 0) {
        const int seg = col >> 10;
        const int lc = col & 1023;
        if (seg == 2) {
          u16* vt = (u16*)O2;
          const size_t off =
              ((size_t)((row0 >> 11) * 16 + (lc >> 6)) * 64 + (lc & 63)) * 2048 +
              (row0 & 2047);
          ushort4 pk = {f2bf(acc[m][n][0]), f2bf(acc[m][n][1]),
                        f2bf(acc[m][n][2]), f2bf(acc[m][n][3])};
          *(ushort4*)(vt + off) = pk;
        } else {
          u16* o = (u16*)(seg == 0 ? O0 : O1);
#pragma unroll
          for (int r = 0; r < 4; ++r)
            o[(size_t)(row0 + r) * 1024 + lc] = f2bf(acc[m][n][r]);
        }
      } else {
        const float bv = bias[col];
#pragma unroll
        for (int r = 0; r < 4; ++r) {
          float v = acc[m][n][r] + bv;
          v = v > 0.f ? v : 0.f;
          ((u16*)O0)[(size_t)(row0 + r) * N + col] = f2bf(v);
        }
      }
    }
  }
}

// ---------------- GEMM 64x128, BK=64, 3-buffer, single barrier/iter ---------
// EPI 0: res f32, out bf16 (proj -> x1).  EPI 1: res bf16, out f32 (final).

template <int EPI>
__global__ __launch_bounds__(256)
void gemm64(const u16* __restrict__ A, const u16* __restrict__ Bt,
            const float* __restrict__ bias, const void* __restrict__ res,
            void* __restrict__ O, int M, int N, int K) {
  __shared__ __align__(16) u16 Alds[3][64 * 64];    // 8KB each
  __shared__ __align__(16) u16 Blds[3][128 * 64];   // 16KB each
  const int tid = threadIdx.x;
  const int lane = tid & 63, wid = tid >> 6;
  const int rl = lane & 15, kg = lane >> 4;
  int bx, by, bz;
  xcd_swizzle(bx, by, bz);
  const int m0 = by * 64, n0 = bx * 128;
  f32x4 acc[2][4];
#pragma unroll
  for (int i = 0; i < 2; ++i)
#pragma unroll
    for (int j = 0; j < 4; ++j) acc[i][j] = (f32x4){0.f, 0.f, 0.f, 0.f};
  const int wr = wid >> 1, wc = wid & 1;
  const int lrow = lane >> 3;
  const int lslot = lane & 7;

#define SRCA(base_r, k0)                                                       \
  (A + (size_t)(m0 + (base_r) + lrow) * K + (k0) +                             \
   ((lslot ^ (((base_r) + lrow) & 7)) * 8))
#define SRCB(base_r, k0)                                                       \
  (Bt + (size_t)(n0 + (base_r) + lrow) * K + (k0) +                            \
   ((lslot ^ (((base_r) + lrow) & 7)) * 8))

#define STAGE_64(buf, k0)                                                      \
  {                                                                            \
    gll16(Alds[buf] + (wid * 16 + 0) * 64, SRCA(wid * 16 + 0, k0));            \
    gll16(Alds[buf] + (wid * 16 + 8) * 64, SRCA(wid * 16 + 8, k0));            \
    gll16(Blds[buf] + (wid * 32 + 0) * 64, SRCB(wid * 32 + 0, k0));            \
    gll16(Blds[buf] + (wid * 32 + 8) * 64, SRCB(wid * 32 + 8, k0));            \
    gll16(Blds[buf] + (wid * 32 + 16) * 64, SRCB(wid * 32 + 16, k0));          \
    gll16(Blds[buf] + (wid * 32 + 24) * 64, SRCB(wid * 32 + 24, k0));          \
  }

  const int nt = K >> 6;
  STAGE_64(0, 0);
  STAGE_64(1, 64);
  int cur = 0;
  for (int t = 0; t < nt; ++t) {
    if (t + 1 < nt)
      asm volatile("s_waitcnt vmcnt(6)" ::: "memory");
    else
      asm volatile("s_waitcnt vmcnt(0)" ::: "memory");
    __builtin_amdgcn_s_barrier();
    if (t + 2 < nt) {
      const int nxt = cur >= 1 ? cur - 1 : cur + 2;   // (cur+2)%3
      STAGE_64(nxt, (t + 2) << 6);
    }
    bf16x8 af[2][2], bfr[4][2];
#pragma unroll
    for (int m = 0; m < 2; ++m) {
      const int row = wr * 32 + m * 16 + rl;
#pragma unroll
      for (int kf = 0; kf < 2; ++kf)
        af[m][kf] = *(const bf16x8*)(Alds[cur] + row * 64 +
                                     ((kf * 4 + kg) ^ (row & 7)) * 8);
    }
#pragma unroll
    for (int n = 0; n < 4; ++n) {
      const int row = wc * 64 + n * 16 + rl;
#pragma unroll
      for (int kf = 0; kf < 2; ++kf)
        bfr[n][kf] = *(const bf16x8*)(Blds[cur] + row * 64 +
                                      ((kf * 4 + kg) ^ (row & 7)) * 8);
    }
    __builtin_amdgcn_s_setprio(1);
#pragma unroll
    for (int m = 0; m < 2; ++m)
#pragma unroll
      for (int n = 0; n < 4; ++n) {
        acc[m][n] = mfma16(af[m][0], bfr[n][0], acc[m][n]);
        acc[m][n] = mfma16(af[m][1], bfr[n][1], acc[m][n]);
      }
    __builtin_amdgcn_s_setprio(0);
    cur = cur + 1 == 3 ? 0 : cur + 1;
  }
#undef STAGE_64
#undef SRCA
#undef SRCB

#pragma unroll
  for (int m = 0; m < 2; ++m) {
#pragma unroll
    for (int n = 0; n < 4; ++n) {
      const int col = n0 + wc * 64 + n * 16 + rl;
      const int row0 = m0 + wr * 32 + m * 16 + kg * 4;
      const float bv = bias[col];
#pragma unroll
      for (int r = 0; r < 4; ++r) {
        const int row = row0 + r;
        if (EPI == 0) {
          const float rv = ((const float*)res)[(size_t)row * N + col];
          ((u16*)O)[(size_t)row * N + col] = f2bf(acc[m][n][r] + bv + rv);
        } else {
          const float rv = b2f(((const u16*)res)[(size_t)row * N + col]);
          ((float*)O)[(size_t)row * N + col] = acc[m][n][r] + bv + rv;
        }
      }
    }
  }
}

// ---------------- causal flash attention: 4-wave chunked pair blocks --------
// Block = 256 thr (4 waves) owning pair (jA=pr, jB=63-pr); total iters
// nA+nB = 33 split into contiguous chunks of 8-9 per wave (perfect balance
// at wave AND block granularity).  Fixed-shift softmax => partials merge by
// ADDITION: wave 0 merges subtile A, wave 3 merges subtile B via LDS slots.
// Waves: 4096 (vs 2048) -> ~3 waves/SIMD.

#define SC2 0.045084220027780106f   // (1/32) * log2(e)

__device__ __forceinline__ void attn_range(
    const u16* __restrict__ qg, const u16* __restrict__ kgl,
    const u16* __restrict__ vtb, size_t rowb, int cb, char* plw,
    int rl, int kg, int q0, int kvb, int kve, bool mask_last,
    f32x4 (&ot)[2][4], float (&lrun)[2]) {
  if (kvb >= kve) return;
  const int swz = (rl & 7) << 4;
  bf16x8 qf[2][2];
#pragma unroll
  for (int m = 0; m < 2; ++m) {
    const u16* qp = qg + (rowb + q0 + m * 16 + rl) * 1024 + cb + kg * 8;
    qf[m][0] = *(const bf16x8*)(qp);
    qf[m][1] = *(const bf16x8*)(qp + 32);
  }

  bf16x8 ka[4][2], kb[4][2];
#define LOADK(dst, kvi)                                                        \
  {                                                                            \
    const u16* krow = kgl + (rowb + (kvi) * 64 + rl) * 1024 + cb + kg * 8;     \
    _Pragma("unroll") for (int n = 0; n < 4; ++n) {                            \
      dst[n][0] = *(const bf16x8*)(krow + (size_t)n * 16 * 1024);              \
      dst[n][1] = *(const bf16x8*)(krow + (size_t)n * 16 * 1024 + 32);         \
    }                                                                          \
  }

#define BODY(kf, kvi)                                                          \
  {                                                                            \
    const int kv0 = (kvi) * 64;                                                \
    const u16* vrow = vtb + (size_t)rl * 2048 + kv0 + kg * 8;                  \
    bf16x8 vfr[4][2];                                                          \
    _Pragma("unroll") for (int dt = 0; dt < 4; ++dt) {                         \
      vfr[dt][0] = *(const bf16x8*)(vrow + (size_t)dt * 16 * 2048);            \
      vfr[dt][1] = *(const bf16x8*)(vrow + (size_t)dt * 16 * 2048 + 32);       \
    }                                                                          \
    const bool domask = mask_last && ((kvi) == kve - 1);                       \
    _Pragma("unroll") for (int m = 0; m < 2; ++m) {                            \
      f32x4 s[4];                                                              \
      __builtin_amdgcn_s_setprio(1);                                           \
      _Pragma("unroll") for (int n = 0; n < 4; ++n) {                          \
        f32x4 t = (f32x4){0.f, 0.f, 0.f, 0.f};                                 \
        t = mfma16(kf[n][0], qf[m][0], t);                                     \
        t = mfma16(kf[n][1], qf[m][1], t);                                     \
        s[n] = t;                                                              \
      }                                                                        \
      __builtin_amdgcn_s_setprio(0);                                           \
      if (domask) {                                                            \
        const int qrow = q0 + m * 16 + rl;                                     \
        _Pragma("unroll") for (int n = 0; n < 4; ++n)                          \
            _Pragma("unroll") for (int r = 0; r < 4; ++r) {                    \
          const int tk = kv0 + n * 16 + 4 * kg + r;                            \
          s[n][r] = (tk > qrow) ? -3e38f : s[n][r];                            \
        }                                                                      \
      }                                                                        \
      float ps = 0.f;                                                          \
      _Pragma("unroll") for (int n = 0; n < 4; ++n) {                          \
        const float p0 = fexp2(__builtin_fmaf(s[n][0], SC2, -8.f));            \
        const float p1 = fexp2(__builtin_fmaf(s[n][1], SC2, -8.f));            \
        const float p2 = fexp2(__builtin_fmaf(s[n][2], SC2, -8.f));            \
        const float p3 = fexp2(__builtin_fmaf(s[n][3], SC2, -8.f));            \
        ps += (p0 + p1) + (p2 + p3);                                           \
        ushort4 pk = {f2bf(p0), f2bf(p1), f2bf(p2), f2bf(p3)};                 \
        *(ushort4*)(plw + m * 2048 + ((rl * 128 + n * 32 + kg * 8) ^ swz)) =   \
            pk;                                                                \
      }                                                                        \
      lrun[m] += ps;                                                           \
    }                                                                          \
    _Pragma("unroll") for (int m = 0; m < 2; ++m) {                            \
      const bf16x8 pf0 =                                                       \
          *(const bf16x8*)(plw + m * 2048 + ((rl * 128 + kg * 16) ^ swz));     \
      const bf16x8 pf1 = *(const bf16x8*)(plw + m * 2048 +                     \
                                          ((rl * 128 + 64 + kg * 16) ^ swz));  \
      __builtin_amdgcn_s_setprio(1);                                           \
      _Pragma("unroll") for (int dt = 0; dt < 4; ++dt) {                       \
        ot[m][dt] = mfma16(vfr[dt][0], pf0, ot[m][dt]);                        \
        ot[m][dt] = mfma16(vfr[dt][1], pf1, ot[m][dt]);                        \
      }                                                                        \
      __builtin_amdgcn_s_setprio(0);                                           \
    }                                                                          \
  }

  LOADK(ka, kvb);
  int kv = kvb;
  for (;;) {
    if (kv + 1 < kve) LOADK(kb, kv + 1);
    BODY(ka, kv);
    ++kv;
    if (kv >= kve) break;
    if (kv + 1 < kve) LOADK(ka, kv + 1);
    BODY(kb, kv);
    ++kv;
    if (kv >= kve) break;
  }
#undef LOADK
#undef BODY
}

__global__ __launch_bounds__(256)
void attn_kernel(const u16* __restrict__ qg, const u16* __restrict__ kgl,
                 const u16* __restrict__ vtg, u16* __restrict__ og) {
  const int tid = threadIdx.x, lane = tid & 63, wid = tid >> 6;
  const int rl = lane & 15, kg = lane >> 4;
  const int flat = blockIdx.x;
  const int bh = (flat & 7) * 4 + ((flat >> 3) & 3);
  const int pr = flat >> 5;                       // pair index 0..31
  const int jA = pr, jB = 63 - pr;                // 32-row q-subtiles
  const int nA = (jA >> 1) + 1;                   // nA + nB = 33
  const size_t rowb = (size_t)(bh >> 4) * 2048;
  const int cb = (bh & 15) * 64;
  const u16* vtb = vtg + (size_t)bh * 64 * 2048;

  __shared__ __align__(16) char Pl[4][4096];            // 16KB
  __shared__ __align__(16) f32x4 SlotO[4][2][4][64];    // 32KB
  __shared__ float SlotL[4][2][16];                     // 0.5KB
  char* plw = Pl[wid];

  // wave chunk of the concatenated iter sequence A[0..nA) ++ B[0..nB)
  const int s = (33 * wid) >> 2;                  // 0, 8, 16, 24
  const int e = (33 * (wid + 1)) >> 2;            // 8, 16, 24, 33

  f32x4 ot[2][4];
  float lrun[2] = {0.f, 0.f};
#pragma unroll
  for (int m = 0; m < 2; ++m)
#pragma unroll
    for (int dt = 0; dt < 4; ++dt) ot[m][dt] = (f32x4){0.f, 0.f, 0.f, 0.f};

  // ---- A part: iters [s, min(e, nA)) of subtile jA ----
  {
    const int ae = e < nA ? e : nA;
    if (s < nA)
      attn_range(qg, kgl, vtb, rowb, cb, plw, rl, kg, jA * 32, s, ae,
                 ae == nA, ot, lrun);
  }
  // dump A partial (zeros if untouched)
#pragma unroll
  for (int m = 0; m < 2; ++m) {
    float l = lrun[m];
    l += __shfl_xor(l, 16);
    l += __shfl_xor(l, 32);
#pragma unroll
    for (int dt = 0; dt < 4; ++dt) SlotO[wid][m][dt][lane] = ot[m][dt];
    if (kg == 0) SlotL[wid][m][rl] = l;
    lrun[m] = 0.f;
#pragma unroll
    for (int dt = 0; dt < 4; ++dt) ot[m][dt] = (f32x4){0.f, 0.f, 0.f, 0.f};
  }

  // ---- B part: iters [max(s,nA)-nA, e-nA) of subtile jB ----
  if (e > nA) {
    const int bs = (s > nA ? s : nA) - nA;
    attn_range(qg, kgl, vtb, rowb, cb, plw, rl, kg, jB * 32, bs, e - nA,
               e == 33, ot, lrun);
  }
#pragma unroll
  for (int m = 0; m < 2; ++m) {
    lrun[m] += __shfl_xor(lrun[m], 16);
    lrun[m] += __shfl_xor(lrun[m], 32);
  }

  __syncthreads();
  // ---- merge A (wave 0) ----
  if (wid == 0) {
#pragma unroll
    for (int m = 0; m < 2; ++m) {
      const float l = SlotL[0][m][rl] + SlotL[1][m][rl] +
                      SlotL[2][m][rl] + SlotL[3][m][rl];
      const float inv = 1.f / l;
      u16* orow = og + (rowb + jA * 32 + m * 16 + rl) * 1024 + cb;
#pragma unroll
      for (int dt = 0; dt < 4; ++dt) {
        const f32x4 o = SlotO[0][m][dt][lane] + SlotO[1][m][dt][lane] +
                        SlotO[2][m][dt][lane] + SlotO[3][m][dt][lane];
        ushort4 ok = {f2bf(o[0] * inv), f2bf(o[1] * inv),
                      f2bf(o[2] * inv), f2bf(o[3] * inv)};
        *(ushort4*)(orow + dt * 16 + 4 * kg) = ok;
      }
    }
  }
  __syncthreads();
  // ---- dump B partials into (now free) slots ----
#pragma unroll
  for (int m = 0; m < 2; ++m) {
#pragma unroll
    for (int dt = 0; dt < 4; ++dt) SlotO[wid][m][dt][lane] = ot[m][dt];
    if (kg == 0) SlotL[wid][m][rl] = lrun[m];
  }
  __syncthreads();
  // ---- merge B (wave 3) ----
  if (wid == 3) {
#pragma unroll
    for (int m = 0; m < 2; ++m) {
      const float l = SlotL[0][m][rl] + SlotL[1][m][rl] +
                      SlotL[2][m][rl] + SlotL[3][m][rl];
      const float inv = 1.f / l;
      u16* orow = og + (rowb + jB * 32 + m * 16 + rl) * 1024 + cb;
#pragma unroll
      for (int dt = 0; dt < 4; ++dt) {
        const f32x4 o = SlotO[0][m][dt][lane] + SlotO[1][m][dt][lane] +
                        SlotO[2][m][dt][lane] + SlotO[3][m][dt][lane];
        ushort4 ok = {f2bf(o[0] * inv), f2bf(o[1] * inv),
                      f2bf(o[2] * inv), f2bf(o[3] * inv)};
        *(ushort4*)(orow + dt * 16 + 4 * kg) = ok;
      }
    }
  }
}

// ---------------- launch ----------------

extern "C" void kernel_launch(void* const* d_in, const int* in_sizes, int n_in,
                              void* d_out, int out_size, void* d_ws, size_t ws_size,
                              hipStream_t stream) {
  const float* x    = (const float*)d_in[0];
  const float* Wq   = (const float*)d_in[1];
  const float* Wk   = (const float*)d_in[2];
  const float* Wv   = (const float*)d_in[3];
  const float* Wo   = (const float*)d_in[4];
  const float* bo   = (const float*)d_in[5];
  const float* W1   = (const float*)d_in[6];
  const float* b1   = (const float*)d_in[7];
  const float* W2   = (const float*)d_in[8];
  const float* b2   = (const float*)d_in[9];
  const float* ln1g = (const float*)d_in[10];
  const float* ln1b = (const float*)d_in[11];
  const float* ln2g = (const float*)d_in[12];
  const float* ln2b = (const float*)d_in[13];
  float* out = (float*)d_out;

  char* ws = (char*)d_ws;
  const size_t MB = 1024 * 1024;
  u16* WqT  = (u16*)(ws + 0 * MB);    // [3072][1024] contiguous (Wq,Wk,Wv)
  u16* WoT  = (u16*)(ws + 6 * MB);
  u16* W1T  = (u16*)(ws + 8 * MB);
  u16* W2T  = (u16*)(ws + 16 * MB);
  u16* h    = (u16*)(ws + 24 * MB);
  u16* q    = (u16*)(ws + 32 * MB);
  u16* k    = (u16*)(ws + 40 * MB);
  u16* vt   = (u16*)(ws + 48 * MB);   // [32][64][2048] bf16
  u16* attn = (u16*)(ws + 56 * MB);
  u16* x1b  = (u16*)(ws + 64 * MB);   // [4096][1024] bf16
  u16* ff1  = (u16*)(ws + 32 * MB);   // aliases q/k/vt/attn
  u16* WkT  = WqT + 1024 * 1024;
  u16* WvT  = WqT + 2 * 1024 * 1024;

  dim3 tblk(32, 8);
  transpose_all<<<12288, tblk, 0, stream>>>(Wq, Wk, Wv, Wo, W1, W2,
                                            WqT, WkT, WvT, WoT, W1T, W2T);

  ln_kernel<0><<<4096, 256, 0, stream>>>(x, ln1g, ln1b, h);

  gemm256<0><<<dim3(24, 16), 512, 0, stream>>>(h, WqT, nullptr,
                                               q, k, vt, 4096, 3072, 1024);

  attn_kernel<<<1024, 256, 0, stream>>>(q, k, vt, attn);

  // x1 (bf16) = x + attn @ Wo + bo
  gemm64<0><<<dim3(8, 64), 256, 0, stream>>>(attn, WoT, bo, x, x1b,
                                             4096, 1024, 1024);

  ln_kernel<1><<<4096, 256, 0, stream>>>(x1b, ln2g, ln2b, h);

  gemm256<1><<<dim3(32, 16), 512, 0, stream>>>(h, W1T, b1, ff1, ff1, ff1,
                                               4096, 4096, 1024);

  // out (f32) = x1 + ff1 @ W2 + b2
  gemm64<1><<<dim3(8, 64), 256, 0, stream>>>(ff1, W2T, b2, x1b, out,
                                             4096, 1024, 4096);
}

// Round 16
// 238.037 us; speedup vs baseline: 1.0570x; 1.0570x over previous
//
#include <hip/hip_runtime.h>

typedef unsigned short u16;
typedef __bf16 bf16;
typedef bf16 bf16x8 __attribute__((ext_vector_type(8)));
typedef float f32x4 __attribute__((ext_vector_type(4)));

// ---------------- helpers ----------------

__device__ __forceinline__ u16 f2bf(float f) {
  bf16 b = (bf16)f;
  return __builtin_bit_cast(u16, b);
}

__device__ __forceinline__ float b2f(u16 u) {
  return __uint_as_float(((unsigned)u) << 16);
}

__device__ __forceinline__ float fexp2(float x) {
#if __has_builtin(__builtin_amdgcn_exp2f)
  return __builtin_amdgcn_exp2f(x);
#else
  return exp2f(x);
#endif
}

__device__ __forceinline__ void gll16(void* lds, const void* g) {
  __builtin_amdgcn_global_load_lds((__attribute__((address_space(1))) void*)g,
                                   (__attribute__((address_space(3))) void*)lds,
                                   16, 0, 0);
}

__device__ __forceinline__ f32x4 mfma16(bf16x8 a, bf16x8 b, f32x4 c) {
  return __builtin_amdgcn_mfma_f32_16x16x32_bf16(a, b, c, 0, 0, 0);
}

// ---------------- prep: weight transposes (fp32->bf16 [C][R]) + ln1 fused ---
// blocks [0,12288): transpose tiles; blocks [12288,16384): ln1 rows.

__global__ __launch_bounds__(256)
void prep_kernel(const float* __restrict__ Wq, const float* __restrict__ Wk,
                 const float* __restrict__ Wv, const float* __restrict__ Wo,
                 const float* __restrict__ W1, const float* __restrict__ W2,
                 u16* __restrict__ WqT, u16* __restrict__ WkT,
                 u16* __restrict__ WvT, u16* __restrict__ WoT,
                 u16* __restrict__ W1T, u16* __restrict__ W2T,
                 const float* __restrict__ x, const float* __restrict__ ln1g,
                 const float* __restrict__ ln1b, u16* __restrict__ h) {
  const int id = blockIdx.x;
  const int tid = threadIdx.x;
  if (id < 12288) {
    __shared__ float tile[32][33];
    const int tx = tid & 31, ty = tid >> 5;         // 32 x 8
    const float* src;
    u16* dst;
    int R, C, t;
    if (id < 4096) {
      const int w = id >> 10;
      t = id & 1023; R = 1024; C = 1024;
      src = w == 0 ? Wq : w == 1 ? Wk : w == 2 ? Wv : Wo;
      dst = w == 0 ? WqT : w == 1 ? WkT : w == 2 ? WvT : WoT;
    } else if (id < 8192) {
      t = id - 4096; R = 1024; C = 4096; src = W1; dst = W1T;
    } else {
      t = id - 8192; R = 4096; C = 1024; src = W2; dst = W2T;
    }
    const int tilesx = C >> 5;
    const int c0 = (t % tilesx) * 32, r0 = (t / tilesx) * 32;
#pragma unroll
    for (int i = 0; i < 4; ++i)
      tile[ty + i * 8][tx] = src[(size_t)(r0 + ty + i * 8) * C + c0 + tx];
    __syncthreads();
#pragma unroll
    for (int i = 0; i < 4; ++i)
      dst[(size_t)(c0 + ty + i * 8) * R + r0 + tx] = f2bf(tile[tx][ty + i * 8]);
  } else {
    const int row = id - 12288;
    const float4 xv = ((const float4*)(x + (size_t)row * 1024))[tid];
    float s = xv.x + xv.y + xv.z + xv.w;
    float q = xv.x * xv.x + xv.y * xv.y + xv.z * xv.z + xv.w * xv.w;
#pragma unroll
    for (int m = 1; m < 64; m <<= 1) {
      s += __shfl_xor(s, m);
      q += __shfl_xor(q, m);
    }
    __shared__ float ss[4], qq[4];
    const int wid = tid >> 6, lane = tid & 63;
    if (lane == 0) { ss[wid] = s; qq[wid] = q; }
    __syncthreads();
    s = ss[0] + ss[1] + ss[2] + ss[3];
    q = qq[0] + qq[1] + qq[2] + qq[3];
    const float mean = s * (1.0f / 1024.0f);
    const float var = q * (1.0f / 1024.0f) - mean * mean;
    const float rs = rsqrtf(var + 1e-5f);
    const float4 gv = ((const float4*)ln1g)[tid];
    const float4 bv = ((const float4*)ln1b)[tid];
    ushort4 o;
    o.x = f2bf((xv.x - mean) * rs * gv.x + bv.x);
    o.y = f2bf((xv.y - mean) * rs * gv.y + bv.y);
    o.z = f2bf((xv.z - mean) * rs * gv.z + bv.z);
    o.w = f2bf((xv.w - mean) * rs * gv.w + bv.w);
    ((ushort4*)(h + (size_t)row * 1024))[tid] = o;
  }
}

// ---------------- layernorm (ln2): bf16 row -> bf16 row (C=1024) ------------

__global__ __launch_bounds__(256)
void ln_kernel(const u16* __restrict__ xin, const float* __restrict__ g,
               const float* __restrict__ bb, u16* __restrict__ h) {
  const int row = blockIdx.x;
  const int tid = threadIdx.x;
  float4 xv;
  const ushort4 u = ((const ushort4*)(xin + (size_t)row * 1024))[tid];
  xv.x = b2f(u.x); xv.y = b2f(u.y); xv.z = b2f(u.z); xv.w = b2f(u.w);
  float s = xv.x + xv.y + xv.z + xv.w;
  float q = xv.x * xv.x + xv.y * xv.y + xv.z * xv.z + xv.w * xv.w;
#pragma unroll
  for (int m = 1; m < 64; m <<= 1) {
    s += __shfl_xor(s, m);
    q += __shfl_xor(q, m);
  }
  __shared__ float ss[4], qq[4];
  const int wid = tid >> 6, lane = tid & 63;
  if (lane == 0) { ss[wid] = s; qq[wid] = q; }
  __syncthreads();
  s = ss[0] + ss[1] + ss[2] + ss[3];
  q = qq[0] + qq[1] + qq[2] + qq[3];
  const float mean = s * (1.0f / 1024.0f);
  const float var = q * (1.0f / 1024.0f) - mean * mean;
  const float rs = rsqrtf(var + 1e-5f);
  const float4 gv = ((const float4*)g)[tid];
  const float4 bv = ((const float4*)bb)[tid];
  ushort4 o;
  o.x = f2bf((xv.x - mean) * rs * gv.x + bv.x);
  o.y = f2bf((xv.y - mean) * rs * gv.y + bv.y);
  o.z = f2bf((xv.z - mean) * rs * gv.z + bv.z);
  o.w = f2bf((xv.w - mean) * rs * gv.w + bv.w);
  ((ushort4*)(h + (size_t)row * 1024))[tid] = o;
}

// ---------------- XCD-aware block swizzle (bijective, nwg%8==0) -------------

__device__ __forceinline__ void xcd_swizzle(int& bx, int& by, int& bz) {
  const int gx = gridDim.x, gy = gridDim.y;
  const int nwg = gx * gy * (int)gridDim.z;
  int flat = (int)blockIdx.x + gx * ((int)blockIdx.y + gy * (int)blockIdx.z);
  flat = (flat & 7) * (nwg >> 3) + (flat >> 3);
  bx = flat % gx;
  const int rem = flat / gx;
  by = rem % gy;
  bz = rem / gy;
}

// ---------------- GEMM 256x128, 512 thr / 8 waves, BK=32, 3-buf -------------
// EPI 0: QKV fused (N=3072); col seg 0->q, 1->k, 2->vt [bh][d][t].
// EPI 1: out bf16 = relu(acc + bias).

template <int EPI>
__global__ __launch_bounds__(512)
void gemm256(const u16* __restrict__ A, const u16* __restrict__ Bt,
             const float* __restrict__ bias,
             void* __restrict__ O0, void* __restrict__ O1, void* __restrict__ O2,
             int M, int N, int K) {
  __shared__ __align__(16) u16 Alds[3][256 * 32];   // 16KB each
  __shared__ __align__(16) u16 Blds[3][128 * 32];   // 8KB each
  const int tid = threadIdx.x;
  const int lane = tid & 63, wid = tid >> 6;        // wid 0..7
  const int rl = lane & 15, kg = lane >> 4;
  const int ksw = (rl >> 1) & 3;
  int bx, by, bz;
  xcd_swizzle(bx, by, bz);
  const int m0 = by * 256, n0 = bx * 128;
  f32x4 acc[4][4];
#pragma unroll
  for (int i = 0; i < 4; ++i)
#pragma unroll
    for (int j = 0; j < 4; ++j) acc[i][j] = (f32x4){0.f, 0.f, 0.f, 0.f};
  const int wr = wid >> 1, wc = wid & 1;            // 4x2 wave grid
  const int srow = lane >> 2;                       // 0..15 within instr
  const int skol = (((lane & 3) ^ ((lane >> 3) & 3))) * 8;  // pre-swizzled

#define STAGE_256(buf, k0)                                                     \
  {                                                                            \
    gll16(Alds[buf] + (wid * 32 + 0) * 32,                                     \
          A + (size_t)(m0 + wid * 32 + 0 + srow) * K + (k0) + skol);           \
    gll16(Alds[buf] + (wid * 32 + 16) * 32,                                    \
          A + (size_t)(m0 + wid * 32 + 16 + srow) * K + (k0) + skol);          \
    gll16(Blds[buf] + (wid * 16) * 32,                                         \
          Bt + (size_t)(n0 + wid * 16 + srow) * K + (k0) + skol);              \
  }

  const int nt = K >> 5;
  STAGE_256(0, 0);
  STAGE_256(1, 32);
  int cur = 0;
  for (int t = 0; t < nt; ++t) {
    if (t + 1 < nt)
      asm volatile("s_waitcnt vmcnt(3)" ::: "memory");
    else
      asm volatile("s_waitcnt vmcnt(0)" ::: "memory");
    __builtin_amdgcn_s_barrier();
    if (t + 2 < nt) {
      const int nxt = cur >= 1 ? cur - 1 : cur + 2;   // (cur+2)%3
      STAGE_256(nxt, (t + 2) << 5);
    }
    bf16x8 af[4], bfr[4];
#pragma unroll
    for (int m = 0; m < 4; ++m)
      af[m] = *(const bf16x8*)(Alds[cur] + (wr * 64 + m * 16 + rl) * 32 +
                               (kg ^ ksw) * 8);
#pragma unroll
    for (int n = 0; n < 4; ++n)
      bfr[n] = *(const bf16x8*)(Blds[cur] + (wc * 64 + n * 16 + rl) * 32 +
                                (kg ^ ksw) * 8);
    __builtin_amdgcn_s_setprio(1);
#pragma unroll
    for (int m = 0; m < 4; ++m)
#pragma unroll
      for (int n = 0; n < 4; ++n)
        acc[m][n] = mfma16(af[m], bfr[n], acc[m][n]);
    __builtin_amdgcn_s_setprio(0);
    cur = cur + 1 == 3 ? 0 : cur + 1;
  }
#undef STAGE_256

#pragma unroll
  for (int m = 0; m < 4; ++m) {
#pragma unroll
    for (int n = 0; n < 4; ++n) {
      const int col = n0 + wc * 64 + n * 16 + rl;
      const int row0 = m0 + wr * 64 + m * 16 + kg * 4;
      if (EPI == 0) {
        const int seg = col >> 10;
        const int lc = col & 1023;
        if (seg == 2) {
          u16* vt = (u16*)O2;
          const size_t off =
              ((size_t)((row0 >> 11) * 16 + (lc >> 6)) * 64 + (lc & 63)) * 2048 +
              (row0 & 2047);
          ushort4 pk = {f2bf(acc[m][n][0]), f2bf(acc[m][n][1]),
                        f2bf(acc[m][n][2]), f2bf(acc[m][n][3])};
          *(ushort4*)(vt + off) = pk;
        } else {
          u16* o = (u16*)(seg == 0 ? O0 : O1);
#pragma unroll
          for (int r = 0; r < 4; ++r)
            o[(size_t)(row0 + r) * 1024 + lc] = f2bf(acc[m][n][r]);
        }
      } else {
        const float bv = bias[col];
#pragma unroll
        for (int r = 0; r < 4; ++r) {
          float v = acc[m][n][r] + bv;
          v = v > 0.f ? v : 0.f;
          ((u16*)O0)[(size_t)(row0 + r) * N + col] = f2bf(v);
        }
      }
    }
  }
}

// ---------------- GEMM 64x128, BK=64, 3-buffer, single barrier/iter ---------
// EPI 0: res f32, out bf16 (proj -> x1).  EPI 1: res bf16, out f32 (final).

template <int EPI>
__global__ __launch_bounds__(256)
void gemm64(const u16* __restrict__ A, const u16* __restrict__ Bt,
            const float* __restrict__ bias, const void* __restrict__ res,
            void* __restrict__ O, int M, int N, int K) {
  __shared__ __align__(16) u16 Alds[3][64 * 64];    // 8KB each
  __shared__ __align__(16) u16 Blds[3][128 * 64];   // 16KB each
  const int tid = threadIdx.x;
  const int lane = tid & 63, wid = tid >> 6;
  const int rl = lane & 15, kg = lane >> 4;
  int bx, by, bz;
  xcd_swizzle(bx, by, bz);
  const int m0 = by * 64, n0 = bx * 128;
  f32x4 acc[2][4];
#pragma unroll
  for (int i = 0; i < 2; ++i)
#pragma unroll
    for (int j = 0; j < 4; ++j) acc[i][j] = (f32x4){0.f, 0.f, 0.f, 0.f};
  const int wr = wid >> 1, wc = wid & 1;
  const int lrow = lane >> 3;
  const int lslot = lane & 7;

#define SRCA(base_r, k0)                                                       \
  (A + (size_t)(m0 + (base_r) + lrow) * K + (k0) +                             \
   ((lslot ^ (((base_r) + lrow) & 7)) * 8))
#define SRCB(base_r, k0)                                                       \
  (Bt + (size_t)(n0 + (base_r) + lrow) * K + (k0) +                            \
   ((lslot ^ (((base_r) + lrow) & 7)) * 8))

#define STAGE_64(buf, k0)                                                      \
  {                                                                            \
    gll16(Alds[buf] + (wid * 16 + 0) * 64, SRCA(wid * 16 + 0, k0));            \
    gll16(Alds[buf] + (wid * 16 + 8) * 64, SRCA(wid * 16 + 8, k0));            \
    gll16(Blds[buf] + (wid * 32 + 0) * 64, SRCB(wid * 32 + 0, k0));            \
    gll16(Blds[buf] + (wid * 32 + 8) * 64, SRCB(wid * 32 + 8, k0));            \
    gll16(Blds[buf] + (wid * 32 + 16) * 64, SRCB(wid * 32 + 16, k0));          \
    gll16(Blds[buf] + (wid * 32 + 24) * 64, SRCB(wid * 32 + 24, k0));          \
  }

  const int nt = K >> 6;
  STAGE_64(0, 0);
  STAGE_64(1, 64);
  int cur = 0;
  for (int t = 0; t < nt; ++t) {
    if (t + 1 < nt)
      asm volatile("s_waitcnt vmcnt(6)" ::: "memory");
    else
      asm volatile("s_waitcnt vmcnt(0)" ::: "memory");
    __builtin_amdgcn_s_barrier();
    if (t + 2 < nt) {
      const int nxt = cur >= 1 ? cur - 1 : cur + 2;   // (cur+2)%3
      STAGE_64(nxt, (t + 2) << 6);
    }
    bf16x8 af[2][2], bfr[4][2];
#pragma unroll
    for (int m = 0; m < 2; ++m) {
      const int row = wr * 32 + m * 16 + rl;
#pragma unroll
      for (int kf = 0; kf < 2; ++kf)
        af[m][kf] = *(const bf16x8*)(Alds[cur] + row * 64 +
                                     ((kf * 4 + kg) ^ (row & 7)) * 8);
    }
#pragma unroll
    for (int n = 0; n < 4; ++n) {
      const int row = wc * 64 + n * 16 + rl;
#pragma unroll
      for (int kf = 0; kf < 2; ++kf)
        bfr[n][kf] = *(const bf16x8*)(Blds[cur] + row * 64 +
                                      ((kf * 4 + kg) ^ (row & 7)) * 8);
    }
    __builtin_amdgcn_s_setprio(1);
#pragma unroll
    for (int m = 0; m < 2; ++m)
#pragma unroll
      for (int n = 0; n < 4; ++n) {
        acc[m][n] = mfma16(af[m][0], bfr[n][0], acc[m][n]);
        acc[m][n] = mfma16(af[m][1], bfr[n][1], acc[m][n]);
      }
    __builtin_amdgcn_s_setprio(0);
    cur = cur + 1 == 3 ? 0 : cur + 1;
  }
#undef STAGE_64
#undef SRCA
#undef SRCB

#pragma unroll
  for (int m = 0; m < 2; ++m) {
#pragma unroll
    for (int n = 0; n < 4; ++n) {
      const int col = n0 + wc * 64 + n * 16 + rl;
      const int row0 = m0 + wr * 32 + m * 16 + kg * 4;
      const float bv = bias[col];
#pragma unroll
      for (int r = 0; r < 4; ++r) {
        const int row = row0 + r;
        if (EPI == 0) {
          const float rv = ((const float*)res)[(size_t)row * N + col];
          ((u16*)O)[(size_t)row * N + col] = f2bf(acc[m][n][r] + bv + rv);
        } else {
          const float rv = b2f(((const u16*)res)[(size_t)row * N + col]);
          ((float*)O)[(size_t)row * N + col] = acc[m][n][r] + bv + rv;
        }
      }
    }
  }
}

// ---------------- causal flash attention (balanced pairs, no online max) ----
// r12 structure (proven best): 128-thr blocks, pair (j, 63-j), ~17 kv-iters
// per wave (setup amortized), zero in-loop barriers, LDS merge.

#define SC2 0.045084220027780106f   // (1/32) * log2(e)

__device__ __forceinline__ void attn_range(
    const u16* __restrict__ qg, const u16* __restrict__ kgl,
    const u16* __restrict__ vtb, size_t rowb, int cb, char* plw,
    int rl, int kg, int q0, int kvb, int kve, bool mask_last,
    f32x4 (&ot)[2][4], float (&lrun)[2]) {
  if (kvb >= kve) return;
  const int swz = (rl & 7) << 4;
  bf16x8 qf[2][2];
#pragma unroll
  for (int m = 0; m < 2; ++m) {
    const u16* qp = qg + (rowb + q0 + m * 16 + rl) * 1024 + cb + kg * 8;
    qf[m][0] = *(const bf16x8*)(qp);
    qf[m][1] = *(const bf16x8*)(qp + 32);
  }

  bf16x8 ka[4][2], kb[4][2];
#define LOADK(dst, kvi)                                                        \
  {                                                                            \
    const u16* krow = kgl + (rowb + (kvi) * 64 + rl) * 1024 + cb + kg * 8;     \
    _Pragma("unroll") for (int n = 0; n < 4; ++n) {                            \
      dst[n][0] = *(const bf16x8*)(krow + (size_t)n * 16 * 1024);              \
      dst[n][1] = *(const bf16x8*)(krow + (size_t)n * 16 * 1024 + 32);         \
    }                                                                          \
  }

#define BODY(kf, kvi)                                                          \
  {                                                                            \
    const int kv0 = (kvi) * 64;                                                \
    const u16* vrow = vtb + (size_t)rl * 2048 + kv0 + kg * 8;                  \
    bf16x8 vfr[4][2];                                                          \
    _Pragma("unroll") for (int dt = 0; dt < 4; ++dt) {                         \
      vfr[dt][0] = *(const bf16x8*)(vrow + (size_t)dt * 16 * 2048);            \
      vfr[dt][1] = *(const bf16x8*)(vrow + (size_t)dt * 16 * 2048 + 32);       \
    }                                                                          \
    const bool domask = mask_last && ((kvi) == kve - 1);                       \
    _Pragma("unroll") for (int m = 0; m < 2; ++m) {                            \
      f32x4 s[4];                                                              \
      __builtin_amdgcn_s_setprio(1);                                           \
      _Pragma("unroll") for (int n = 0; n < 4; ++n) {                          \
        f32x4 t = (f32x4){0.f, 0.f, 0.f, 0.f};                                 \
        t = mfma16(kf[n][0], qf[m][0], t);                                     \
        t = mfma16(kf[n][1], qf[m][1], t);                                     \
        s[n] = t;                                                              \
      }                                                                        \
      __builtin_amdgcn_s_setprio(0);                                           \
      if (domask) {                                                            \
        const int qrow = q0 + m * 16 + rl;                                     \
        _Pragma("unroll") for (int n = 0; n < 4; ++n)                          \
            _Pragma("unroll") for (int r = 0; r < 4; ++r) {                    \
          const int tk = kv0 + n * 16 + 4 * kg + r;                            \
          s[n][r] = (tk > qrow) ? -3e38f : s[n][r];                            \
        }                                                                      \
      }                                                                        \
      float ps = 0.f;                                                          \
      _Pragma("unroll") for (int n = 0; n < 4; ++n) {                          \
        const float p0 = fexp2(__builtin_fmaf(s[n][0], SC2, -8.f));            \
        const float p1 = fexp2(__builtin_fmaf(s[n][1], SC2, -8.f));            \
        const float p2 = fexp2(__builtin_fmaf(s[n][2], SC2, -8.f));            \
        const float p3 = fexp2(__builtin_fmaf(s[n][3], SC2, -8.f));            \
        ps += (p0 + p1) + (p2 + p3);                                           \
        ushort4 pk = {f2bf(p0), f2bf(p1), f2bf(p2), f2bf(p3)};                 \
        *(ushort4*)(plw + m * 2048 + ((rl * 128 + n * 32 + kg * 8) ^ swz)) =   \
            pk;                                                                \
      }                                                                        \
      lrun[m] += ps;                                                           \
    }                                                                          \
    _Pragma("unroll") for (int m = 0; m < 2; ++m) {                            \
      const bf16x8 pf0 =                                                       \
          *(const bf16x8*)(plw + m * 2048 + ((rl * 128 + kg * 16) ^ swz));     \
      const bf16x8 pf1 = *(const bf16x8*)(plw + m * 2048 +                     \
                                          ((rl * 128 + 64 + kg * 16) ^ swz));  \
      __builtin_amdgcn_s_setprio(1);                                           \
      _Pragma("unroll") for (int dt = 0; dt < 4; ++dt) {                       \
        ot[m][dt] = mfma16(vfr[dt][0], pf0, ot[m][dt]);                        \
        ot[m][dt] = mfma16(vfr[dt][1], pf1, ot[m][dt]);                        \
      }                                                                        \
      __builtin_amdgcn_s_setprio(0);                                           \
    }                                                                          \
  }

  LOADK(ka, kvb);
  int kv = kvb;
  for (;;) {
    if (kv + 1 < kve) LOADK(kb, kv + 1);
    BODY(ka, kv);
    ++kv;
    if (kv >= kve) break;
    if (kv + 1 < kve) LOADK(ka, kv + 1);
    BODY(kb, kv);
    ++kv;
    if (kv >= kve) break;
  }
#undef LOADK
#undef BODY
}

__global__ __launch_bounds__(128)
void attn_kernel(const u16* __restrict__ qg, const u16* __restrict__ kgl,
                 const u16* __restrict__ vtg, u16* __restrict__ og) {
  const int tid = threadIdx.x, lane = tid & 63, wid = tid >> 6;
  const int rl = lane & 15, kg = lane >> 4;
  const int flat = blockIdx.x;
  const int bh = (flat & 7) * 4 + ((flat >> 3) & 3);
  const int pr = flat >> 5;                       // pair index 0..31
  const int jA = pr, jB = 63 - pr;                // 32-row q-subtiles
  const int nA = (jA >> 1) + 1, nB = (jB >> 1) + 1;
  const int a = (nB - nA) >> 1;                   // wave0's share of B
  const size_t rowb = (size_t)(bh >> 4) * 2048;
  const int cb = (bh & 15) * 64;
  const u16* vtb = vtg + (size_t)bh * 64 * 2048;

  __shared__ __align__(16) char Pl[2][4096];
  __shared__ __align__(16) float MrgO[2][4][64][4];   // [m][dt][lane][r]
  __shared__ float MrgL[2][16];
  char* plw = Pl[wid];

  f32x4 ot[2][4];
  float lrun[2] = {0.f, 0.f};
#pragma unroll
  for (int m = 0; m < 2; ++m)
#pragma unroll
    for (int dt = 0; dt < 4; ++dt) ot[m][dt] = (f32x4){0.f, 0.f, 0.f, 0.f};

  if (wid == 0) {
    // subtile A complete
    attn_range(qg, kgl, vtb, rowb, cb, plw, rl, kg, jA * 32, 0, nA, true,
               ot, lrun);
#pragma unroll
    for (int m = 0; m < 2; ++m) {
      lrun[m] += __shfl_xor(lrun[m], 16);
      lrun[m] += __shfl_xor(lrun[m], 32);
      const float inv = 1.f / lrun[m];
      u16* orow = og + (rowb + jA * 32 + m * 16 + rl) * 1024 + cb;
#pragma unroll
      for (int dt = 0; dt < 4; ++dt) {
        ushort4 ok = {f2bf(ot[m][dt][0] * inv), f2bf(ot[m][dt][1] * inv),
                      f2bf(ot[m][dt][2] * inv), f2bf(ot[m][dt][3] * inv)};
        *(ushort4*)(orow + dt * 16 + 4 * kg) = ok;
      }
      lrun[m] = 0.f;
#pragma unroll
      for (int dt = 0; dt < 4; ++dt) ot[m][dt] = (f32x4){0.f, 0.f, 0.f, 0.f};
    }
    // subtile B head [0, a)
    attn_range(qg, kgl, vtb, rowb, cb, plw, rl, kg, jB * 32, 0, a, false,
               ot, lrun);
  } else {
    // subtile B tail [a, nB) incl. diagonal
    attn_range(qg, kgl, vtb, rowb, cb, plw, rl, kg, jB * 32, a, nB, true,
               ot, lrun);
#pragma unroll
    for (int m = 0; m < 2; ++m) {
      lrun[m] += __shfl_xor(lrun[m], 16);
      lrun[m] += __shfl_xor(lrun[m], 32);
#pragma unroll
      for (int dt = 0; dt < 4; ++dt)
        *(f32x4*)(&MrgO[m][dt][lane][0]) = ot[m][dt];
      if (kg == 0) MrgL[m][rl] = lrun[m];
    }
  }
  __syncthreads();
  if (wid == 0) {
#pragma unroll
    for (int m = 0; m < 2; ++m) {
      lrun[m] += __shfl_xor(lrun[m], 16);
      lrun[m] += __shfl_xor(lrun[m], 32);
      const float inv = 1.f / (lrun[m] + MrgL[m][rl]);
      u16* orow = og + (rowb + jB * 32 + m * 16 + rl) * 1024 + cb;
#pragma unroll
      for (int dt = 0; dt < 4; ++dt) {
        const f32x4 o1 = *(const f32x4*)(&MrgO[m][dt][lane][0]);
        ushort4 ok;
#pragma unroll
        for (int r = 0; r < 4; ++r)
          ((u16*)&ok)[r] = f2bf((ot[m][dt][r] + o1[r]) * inv);
        *(ushort4*)(orow + dt * 16 + 4 * kg) = ok;
      }
    }
  }
}

// ---------------- launch ----------------

extern "C" void kernel_launch(void* const* d_in, const int* in_sizes, int n_in,
                              void* d_out, int out_size, void* d_ws, size_t ws_size,
                              hipStream_t stream) {
  const float* x    = (const float*)d_in[0];
  const float* Wq   = (const float*)d_in[1];
  const float* Wk   = (const float*)d_in[2];
  const float* Wv   = (const float*)d_in[3];
  const float* Wo   = (const float*)d_in[4];
  const float* bo   = (const float*)d_in[5];
  const float* W1   = (const float*)d_in[6];
  const float* b1   = (const float*)d_in[7];
  const float* W2   = (const float*)d_in[8];
  const float* b2   = (const float*)d_in[9];
  const float* ln1g = (const float*)d_in[10];
  const float* ln1b = (const float*)d_in[11];
  const float* ln2g = (const float*)d_in[12];
  const float* ln2b = (const float*)d_in[13];
  float* out = (float*)d_out;

  char* ws = (char*)d_ws;
  const size_t MB = 1024 * 1024;
  u16* WqT  = (u16*)(ws + 0 * MB);    // [3072][1024] contiguous (Wq,Wk,Wv)
  u16* WoT  = (u16*)(ws + 6 * MB);
  u16* W1T  = (u16*)(ws + 8 * MB);
  u16* W2T  = (u16*)(ws + 16 * MB);
  u16* h    = (u16*)(ws + 24 * MB);
  u16* q    = (u16*)(ws + 32 * MB);
  u16* k    = (u16*)(ws + 40 * MB);
  u16* vt   = (u16*)(ws + 48 * MB);   // [32][64][2048] bf16
  u16* attn = (u16*)(ws + 56 * MB);
  u16* x1b  = (u16*)(ws + 64 * MB);   // [4096][1024] bf16
  u16* ff1  = (u16*)(ws + 32 * MB);   // aliases q/k/vt/attn
  u16* WkT  = WqT + 1024 * 1024;
  u16* WvT  = WqT + 2 * 1024 * 1024;

  // transposes + ln1 fused
  prep_kernel<<<16384, 256, 0, stream>>>(Wq, Wk, Wv, Wo, W1, W2,
                                         WqT, WkT, WvT, WoT, W1T, W2T,
                                         x, ln1g, ln1b, h);

  // QKV fused: Bt = [WqT;WkT;WvT] (3072x1024); writes q, k, vt
  gemm256<0><<<dim3(24, 16), 512, 0, stream>>>(h, WqT, nullptr,
                                               q, k, vt, 4096, 3072, 1024);

  attn_kernel<<<1024, 128, 0, stream>>>(q, k, vt, attn);

  // x1 (bf16) = x + attn @ Wo + bo
  gemm64<0><<<dim3(8, 64), 256, 0, stream>>>(attn, WoT, bo, x, x1b,
                                             4096, 1024, 1024);

  ln_kernel<<<4096, 256, 0, stream>>>(x1b, ln2g, ln2b, h);

  // ff1 = relu(h2 @ W1 + b1)
  gemm256<1><<<dim3(32, 16), 512, 0, stream>>>(h, W1T, b1, ff1, ff1, ff1,
                                               4096, 4096, 1024);

  // out (f32) = x1 + ff1 @ W2 + b2
  gemm64<1><<<dim3(8, 64), 256, 0, stream>>>(ff1, W2T, b2, x1b, out,
                                             4096, 1024, 4096);
}

// Round 17
// 237.847 us; speedup vs baseline: 1.0578x; 1.0008x over previous
//
#include <hip/hip_runtime.h>

typedef unsigned short u16;
typedef __bf16 bf16;
typedef bf16 bf16x8 __attribute__((ext_vector_type(8)));
typedef float f32x4 __attribute__((ext_vector_type(4)));

// ---------------- helpers ----------------

__device__ __forceinline__ u16 f2bf(float f) {
  bf16 b = (bf16)f;
  return __builtin_bit_cast(u16, b);
}

__device__ __forceinline__ float b2f(u16 u) {
  return __uint_as_float(((unsigned)u) << 16);
}

__device__ __forceinline__ float fexp2(float x) {
#if __has_builtin(__builtin_amdgcn_exp2f)
  return __builtin_amdgcn_exp2f(x);
#else
  return exp2f(x);
#endif
}

__device__ __forceinline__ void gll16(void* lds, const void* g) {
  __builtin_amdgcn_global_load_lds((__attribute__((address_space(1))) void*)g,
                                   (__attribute__((address_space(3))) void*)lds,
                                   16, 0, 0);
}

__device__ __forceinline__ f32x4 mfma16(bf16x8 a, bf16x8 b, f32x4 c) {
  return __builtin_amdgcn_mfma_f32_16x16x32_bf16(a, b, c, 0, 0, 0);
}

// ---------------- prep: weight transposes (fp32->bf16 [C][R]) + ln1 fused ---

__global__ __launch_bounds__(256)
void prep_kernel(const float* __restrict__ Wq, const float* __restrict__ Wk,
                 const float* __restrict__ Wv, const float* __restrict__ Wo,
                 const float* __restrict__ W1, const float* __restrict__ W2,
                 u16* __restrict__ WqT, u16* __restrict__ WkT,
                 u16* __restrict__ WvT, u16* __restrict__ WoT,
                 u16* __restrict__ W1T, u16* __restrict__ W2T,
                 const float* __restrict__ x, const float* __restrict__ ln1g,
                 const float* __restrict__ ln1b, u16* __restrict__ h) {
  const int id = blockIdx.x;
  const int tid = threadIdx.x;
  if (id < 12288) {
    __shared__ float tile[32][33];
    const int tx = tid & 31, ty = tid >> 5;         // 32 x 8
    const float* src;
    u16* dst;
    int R, C, t;
    if (id < 4096) {
      const int w = id >> 10;
      t = id & 1023; R = 1024; C = 1024;
      src = w == 0 ? Wq : w == 1 ? Wk : w == 2 ? Wv : Wo;
      dst = w == 0 ? WqT : w == 1 ? WkT : w == 2 ? WvT : WoT;
    } else if (id < 8192) {
      t = id - 4096; R = 1024; C = 4096; src = W1; dst = W1T;
    } else {
      t = id - 8192; R = 4096; C = 1024; src = W2; dst = W2T;
    }
    const int tilesx = C >> 5;
    const int c0 = (t % tilesx) * 32, r0 = (t / tilesx) * 32;
#pragma unroll
    for (int i = 0; i < 4; ++i)
      tile[ty + i * 8][tx] = src[(size_t)(r0 + ty + i * 8) * C + c0 + tx];
    __syncthreads();
#pragma unroll
    for (int i = 0; i < 4; ++i)
      dst[(size_t)(c0 + ty + i * 8) * R + r0 + tx] = f2bf(tile[tx][ty + i * 8]);
  } else {
    const int row = id - 12288;
    const float4 xv = ((const float4*)(x + (size_t)row * 1024))[tid];
    float s = xv.x + xv.y + xv.z + xv.w;
    float q = xv.x * xv.x + xv.y * xv.y + xv.z * xv.z + xv.w * xv.w;
#pragma unroll
    for (int m = 1; m < 64; m <<= 1) {
      s += __shfl_xor(s, m);
      q += __shfl_xor(q, m);
    }
    __shared__ float ss[4], qq[4];
    const int wid = tid >> 6, lane = tid & 63;
    if (lane == 0) { ss[wid] = s; qq[wid] = q; }
    __syncthreads();
    s = ss[0] + ss[1] + ss[2] + ss[3];
    q = qq[0] + qq[1] + qq[2] + qq[3];
    const float mean = s * (1.0f / 1024.0f);
    const float var = q * (1.0f / 1024.0f) - mean * mean;
    const float rs = rsqrtf(var + 1e-5f);
    const float4 gv = ((const float4*)ln1g)[tid];
    const float4 bv = ((const float4*)ln1b)[tid];
    ushort4 o;
    o.x = f2bf((xv.x - mean) * rs * gv.x + bv.x);
    o.y = f2bf((xv.y - mean) * rs * gv.y + bv.y);
    o.z = f2bf((xv.z - mean) * rs * gv.z + bv.z);
    o.w = f2bf((xv.w - mean) * rs * gv.w + bv.w);
    ((ushort4*)(h + (size_t)row * 1024))[tid] = o;
  }
}

// ---------------- layernorm (ln2): bf16 row -> bf16 row (C=1024) ------------

__global__ __launch_bounds__(256)
void ln_kernel(const u16* __restrict__ xin, const float* __restrict__ g,
               const float* __restrict__ bb, u16* __restrict__ h) {
  const int row = blockIdx.x;
  const int tid = threadIdx.x;
  float4 xv;
  const ushort4 u = ((const ushort4*)(xin + (size_t)row * 1024))[tid];
  xv.x = b2f(u.x); xv.y = b2f(u.y); xv.z = b2f(u.z); xv.w = b2f(u.w);
  float s = xv.x + xv.y + xv.z + xv.w;
  float q = xv.x * xv.x + xv.y * xv.y + xv.z * xv.z + xv.w * xv.w;
#pragma unroll
  for (int m = 1; m < 64; m <<= 1) {
    s += __shfl_xor(s, m);
    q += __shfl_xor(q, m);
  }
  __shared__ float ss[4], qq[4];
  const int wid = tid >> 6, lane = tid & 63;
  if (lane == 0) { ss[wid] = s; qq[wid] = q; }
  __syncthreads();
  s = ss[0] + ss[1] + ss[2] + ss[3];
  q = qq[0] + qq[1] + qq[2] + qq[3];
  const float mean = s * (1.0f / 1024.0f);
  const float var = q * (1.0f / 1024.0f) - mean * mean;
  const float rs = rsqrtf(var + 1e-5f);
  const float4 gv = ((const float4*)g)[tid];
  const float4 bv = ((const float4*)bb)[tid];
  ushort4 o;
  o.x = f2bf((xv.x - mean) * rs * gv.x + bv.x);
  o.y = f2bf((xv.y - mean) * rs * gv.y + bv.y);
  o.z = f2bf((xv.z - mean) * rs * gv.z + bv.z);
  o.w = f2bf((xv.w - mean) * rs * gv.w + bv.w);
  ((ushort4*)(h + (size_t)row * 1024))[tid] = o;
}

// ---------------- XCD-aware block swizzle (bijective, nwg%8==0) -------------

__device__ __forceinline__ void xcd_swizzle(int& bx, int& by, int& bz) {
  const int gx = gridDim.x, gy = gridDim.y;
  const int nwg = gx * gy * (int)gridDim.z;
  int flat = (int)blockIdx.x + gx * ((int)blockIdx.y + gy * (int)blockIdx.z);
  flat = (flat & 7) * (nwg >> 3) + (flat >> 3);
  bx = flat % gx;
  const int rem = flat / gx;
  by = rem % gy;
  bz = rem / gy;
}

// ---------------- GEMM 256x128, 512 thr / 8 waves, BK=32, 3-buf -------------
// EPI 0: QKV fused (N=3072); col seg 0->q, 1->k, 2->vt [bh][d][t].
// EPI 1: out bf16 = relu(acc + bias).

template <int EPI>
__global__ __launch_bounds__(512)
void gemm256(const u16* __restrict__ A, const u16* __restrict__ Bt,
             const float* __restrict__ bias,
             void* __restrict__ O0, void* __restrict__ O1, void* __restrict__ O2,
             int M, int N, int K) {
  __shared__ __align__(16) u16 Alds[3][256 * 32];   // 16KB each
  __shared__ __align__(16) u16 Blds[3][128 * 32];   // 8KB each
  const int tid = threadIdx.x;
  const int lane = tid & 63, wid = tid >> 6;        // wid 0..7
  const int rl = lane & 15, kg = lane >> 4;
  const int ksw = (rl >> 1) & 3;
  int bx, by, bz;
  xcd_swizzle(bx, by, bz);
  const int m0 = by * 256, n0 = bx * 128;
  f32x4 acc[4][4];
#pragma unroll
  for (int i = 0; i < 4; ++i)
#pragma unroll
    for (int j = 0; j < 4; ++j) acc[i][j] = (f32x4){0.f, 0.f, 0.f, 0.f};
  const int wr = wid >> 1, wc = wid & 1;            // 4x2 wave grid
  const int srow = lane >> 2;                       // 0..15 within instr
  const int skol = (((lane & 3) ^ ((lane >> 3) & 3))) * 8;  // pre-swizzled

#define STAGE_256(buf, k0)                                                     \
  {                                                                            \
    gll16(Alds[buf] + (wid * 32 + 0) * 32,                                     \
          A + (size_t)(m0 + wid * 32 + 0 + srow) * K + (k0) + skol);           \
    gll16(Alds[buf] + (wid * 32 + 16) * 32,                                    \
          A + (size_t)(m0 + wid * 32 + 16 + srow) * K + (k0) + skol);          \
    gll16(Blds[buf] + (wid * 16) * 32,                                         \
          Bt + (size_t)(n0 + wid * 16 + srow) * K + (k0) + skol);              \
  }

  const int nt = K >> 5;
  STAGE_256(0, 0);
  STAGE_256(1, 32);
  int cur = 0;
  for (int t = 0; t < nt; ++t) {
    if (t + 1 < nt)
      asm volatile("s_waitcnt vmcnt(3)" ::: "memory");
    else
      asm volatile("s_waitcnt vmcnt(0)" ::: "memory");
    __builtin_amdgcn_s_barrier();
    if (t + 2 < nt) {
      const int nxt = cur >= 1 ? cur - 1 : cur + 2;   // (cur+2)%3
      STAGE_256(nxt, (t + 2) << 5);
    }
    bf16x8 af[4], bfr[4];
#pragma unroll
    for (int m = 0; m < 4; ++m)
      af[m] = *(const bf16x8*)(Alds[cur] + (wr * 64 + m * 16 + rl) * 32 +
                               (kg ^ ksw) * 8);
#pragma unroll
    for (int n = 0; n < 4; ++n)
      bfr[n] = *(const bf16x8*)(Blds[cur] + (wc * 64 + n * 16 + rl) * 32 +
                                (kg ^ ksw) * 8);
    __builtin_amdgcn_s_setprio(1);
#pragma unroll
    for (int m = 0; m < 4; ++m)
#pragma unroll
      for (int n = 0; n < 4; ++n)
        acc[m][n] = mfma16(af[m], bfr[n], acc[m][n]);
    __builtin_amdgcn_s_setprio(0);
    cur = cur + 1 == 3 ? 0 : cur + 1;
  }
#undef STAGE_256

#pragma unroll
  for (int m = 0; m < 4; ++m) {
#pragma unroll
    for (int n = 0; n < 4; ++n) {
      const int col = n0 + wc * 64 + n * 16 + rl;
      const int row0 = m0 + wr * 64 + m * 16 + kg * 4;
      if (EPI == 0) {
        const int seg = col >> 10;
        const int lc = col & 1023;
        if (seg == 2) {
          u16* vt = (u16*)O2;
          const size_t off =
              ((size_t)((row0 >> 11) * 16 + (lc >> 6)) * 64 + (lc & 63)) * 2048 +
              (row0 & 2047);
          ushort4 pk = {f2bf(acc[m][n][0]), f2bf(acc[m][n][1]),
                        f2bf(acc[m][n][2]), f2bf(acc[m][n][3])};
          *(ushort4*)(vt + off) = pk;
        } else {
          u16* o = (u16*)(seg == 0 ? O0 : O1);
#pragma unroll
          for (int r = 0; r < 4; ++r)
            o[(size_t)(row0 + r) * 1024 + lc] = f2bf(acc[m][n][r]);
        }
      } else {
        const float bv = bias[col];
#pragma unroll
        for (int r = 0; r < 4; ++r) {
          float v = acc[m][n][r] + bv;
          v = v > 0.f ? v : 0.f;
          ((u16*)O0)[(size_t)(row0 + r) * N + col] = f2bf(v);
        }
      }
    }
  }
}

// ---------------- GEMM 64x128, BK=64, 3-buffer, single barrier/iter ---------
// EPI 0: res f32, out bf16 (proj -> x1).  EPI 1: res bf16, out f32 (final).

template <int EPI>
__global__ __launch_bounds__(256)
void gemm64(const u16* __restrict__ A, const u16* __restrict__ Bt,
            const float* __restrict__ bias, const void* __restrict__ res,
            void* __restrict__ O, int M, int N, int K) {
  __shared__ __align__(16) u16 Alds[3][64 * 64];    // 8KB each
  __shared__ __align__(16) u16 Blds[3][128 * 64];   // 16KB each
  const int tid = threadIdx.x;
  const int lane = tid & 63, wid = tid >> 6;
  const int rl = lane & 15, kg = lane >> 4;
  int bx, by, bz;
  xcd_swizzle(bx, by, bz);
  const int m0 = by * 64, n0 = bx * 128;
  f32x4 acc[2][4];
#pragma unroll
  for (int i = 0; i < 2; ++i)
#pragma unroll
    for (int j = 0; j < 4; ++j) acc[i][j] = (f32x4){0.f, 0.f, 0.f, 0.f};
  const int wr = wid >> 1, wc = wid & 1;
  const int lrow = lane >> 3;
  const int lslot = lane & 7;

#define SRCA(base_r, k0)                                                       \
  (A + (size_t)(m0 + (base_r) + lrow) * K + (k0) +                             \
   ((lslot ^ (((base_r) + lrow) & 7)) * 8))
#define SRCB(base_r, k0)                                                       \
  (Bt + (size_t)(n0 + (base_r) + lrow) * K + (k0) +                            \
   ((lslot ^ (((base_r) + lrow) & 7)) * 8))

#define STAGE_64(buf, k0)                                                      \
  {                                                                            \
    gll16(Alds[buf] + (wid * 16 + 0) * 64, SRCA(wid * 16 + 0, k0));            \
    gll16(Alds[buf] + (wid * 16 + 8) * 64, SRCA(wid * 16 + 8, k0));            \
    gll16(Blds[buf] + (wid * 32 + 0) * 64, SRCB(wid * 32 + 0, k0));            \
    gll16(Blds[buf] + (wid * 32 + 8) * 64, SRCB(wid * 32 + 8, k0));            \
    gll16(Blds[buf] + (wid * 32 + 16) * 64, SRCB(wid * 32 + 16, k0));          \
    gll16(Blds[buf] + (wid * 32 + 24) * 64, SRCB(wid * 32 + 24, k0));          \
  }

  const int nt = K >> 6;
  STAGE_64(0, 0);
  STAGE_64(1, 64);
  int cur = 0;
  for (int t = 0; t < nt; ++t) {
    if (t + 1 < nt)
      asm volatile("s_waitcnt vmcnt(6)" ::: "memory");
    else
      asm volatile("s_waitcnt vmcnt(0)" ::: "memory");
    __builtin_amdgcn_s_barrier();
    if (t + 2 < nt) {
      const int nxt = cur >= 1 ? cur - 1 : cur + 2;   // (cur+2)%3
      STAGE_64(nxt, (t + 2) << 6);
    }
    bf16x8 af[2][2], bfr[4][2];
#pragma unroll
    for (int m = 0; m < 2; ++m) {
      const int row = wr * 32 + m * 16 + rl;
#pragma unroll
      for (int kf = 0; kf < 2; ++kf)
        af[m][kf] = *(const bf16x8*)(Alds[cur] + row * 64 +
                                     ((kf * 4 + kg) ^ (row & 7)) * 8);
    }
#pragma unroll
    for (int n = 0; n < 4; ++n) {
      const int row = wc * 64 + n * 16 + rl;
#pragma unroll
      for (int kf = 0; kf < 2; ++kf)
        bfr[n][kf] = *(const bf16x8*)(Blds[cur] + row * 64 +
                                      ((kf * 4 + kg) ^ (row & 7)) * 8);
    }
    __builtin_amdgcn_s_setprio(1);
#pragma unroll
    for (int m = 0; m < 2; ++m)
#pragma unroll
      for (int n = 0; n < 4; ++n) {
        acc[m][n] = mfma16(af[m][0], bfr[n][0], acc[m][n]);
        acc[m][n] = mfma16(af[m][1], bfr[n][1], acc[m][n]);
      }
    __builtin_amdgcn_s_setprio(0);
    cur = cur + 1 == 3 ? 0 : cur + 1;
  }
#undef STAGE_64
#undef SRCA
#undef SRCB

#pragma unroll
  for (int m = 0; m < 2; ++m) {
#pragma unroll
    for (int n = 0; n < 4; ++n) {
      const int col = n0 + wc * 64 + n * 16 + rl;
      const int row0 = m0 + wr * 32 + m * 16 + kg * 4;
      const float bv = bias[col];
#pragma unroll
      for (int r = 0; r < 4; ++r) {
        const int row = row0 + r;
        if (EPI == 0) {
          const float rv = ((const float*)res)[(size_t)row * N + col];
          ((u16*)O)[(size_t)row * N + col] = f2bf(acc[m][n][r] + bv + rv);
        } else {
          const float rv = b2f(((const u16*)res)[(size_t)row * N + col]);
          ((float*)O)[(size_t)row * N + col] = acc[m][n][r] + bv + rv;
        }
      }
    }
  }
}

// ---------------- causal flash attention (balanced pairs, P double-buffer) --
// r12 structure + P LDS double-buffered by kv parity: removes the LDS WAR
// hazard between consecutive BODYs (P-write(t+1) no longer waits on
// P-read(t)), letting the scheduler overlap QK(t+1)/loads with PV(t).

#define SC2 0.045084220027780106f   // (1/32) * log2(e)

__device__ __forceinline__ void attn_range(
    const u16* __restrict__ qg, const u16* __restrict__ kgl,
    const u16* __restrict__ vtb, size_t rowb, int cb, char* plw,
    int rl, int kg, int q0, int kvb, int kve, bool mask_last,
    f32x4 (&ot)[2][4], float (&lrun)[2]) {
  if (kvb >= kve) return;
  const int swz = (rl & 7) << 4;
  bf16x8 qf[2][2];
#pragma unroll
  for (int m = 0; m < 2; ++m) {
    const u16* qp = qg + (rowb + q0 + m * 16 + rl) * 1024 + cb + kg * 8;
    qf[m][0] = *(const bf16x8*)(qp);
    qf[m][1] = *(const bf16x8*)(qp + 32);
  }

  bf16x8 ka[4][2], kb[4][2];
#define LOADK(dst, kvi)                                                        \
  {                                                                            \
    const u16* krow = kgl + (rowb + (kvi) * 64 + rl) * 1024 + cb + kg * 8;     \
    _Pragma("unroll") for (int n = 0; n < 4; ++n) {                            \
      dst[n][0] = *(const bf16x8*)(krow + (size_t)n * 16 * 1024);              \
      dst[n][1] = *(const bf16x8*)(krow + (size_t)n * 16 * 1024 + 32);         \
    }                                                                          \
  }

#define BODY(kf, kvi, pw)                                                      \
  {                                                                            \
    const int kv0 = (kvi) * 64;                                                \
    const u16* vrow = vtb + (size_t)rl * 2048 + kv0 + kg * 8;                  \
    bf16x8 vfr[4][2];                                                          \
    _Pragma("unroll") for (int dt = 0; dt < 4; ++dt) {                         \
      vfr[dt][0] = *(const bf16x8*)(vrow + (size_t)dt * 16 * 2048);            \
      vfr[dt][1] = *(const bf16x8*)(vrow + (size_t)dt * 16 * 2048 + 32);       \
    }                                                                          \
    const bool domask = mask_last && ((kvi) == kve - 1);                       \
    _Pragma("unroll") for (int m = 0; m < 2; ++m) {                            \
      f32x4 s[4];                                                              \
      __builtin_amdgcn_s_setprio(1);                                           \
      _Pragma("unroll") for (int n = 0; n < 4; ++n) {                          \
        f32x4 t = (f32x4){0.f, 0.f, 0.f, 0.f};                                 \
        t = mfma16(kf[n][0], qf[m][0], t);                                     \
        t = mfma16(kf[n][1], qf[m][1], t);                                     \
        s[n] = t;                                                              \
      }                                                                        \
      __builtin_amdgcn_s_setprio(0);                                           \
      if (domask) {                                                            \
        const int qrow = q0 + m * 16 + rl;                                     \
        _Pragma("unroll") for (int n = 0; n < 4; ++n)                          \
            _Pragma("unroll") for (int r = 0; r < 4; ++r) {                    \
          const int tk = kv0 + n * 16 + 4 * kg + r;                            \
          s[n][r] = (tk > qrow) ? -3e38f : s[n][r];                            \
        }                                                                      \
      }                                                                        \
      float ps = 0.f;                                                          \
      _Pragma("unroll") for (int n = 0; n < 4; ++n) {                          \
        const float p0 = fexp2(__builtin_fmaf(s[n][0], SC2, -8.f));            \
        const float p1 = fexp2(__builtin_fmaf(s[n][1], SC2, -8.f));            \
        const float p2 = fexp2(__builtin_fmaf(s[n][2], SC2, -8.f));            \
        const float p3 = fexp2(__builtin_fmaf(s[n][3], SC2, -8.f));            \
        ps += (p0 + p1) + (p2 + p3);                                           \
        ushort4 pk = {f2bf(p0), f2bf(p1), f2bf(p2), f2bf(p3)};                 \
        *(ushort4*)((pw) + m * 2048 + ((rl * 128 + n * 32 + kg * 8) ^ swz)) =  \
            pk;                                                                \
      }                                                                        \
      lrun[m] += ps;                                                           \
    }                                                                          \
    _Pragma("unroll") for (int m = 0; m < 2; ++m) {                            \
      const bf16x8 pf0 =                                                       \
          *(const bf16x8*)((pw) + m * 2048 + ((rl * 128 + kg * 16) ^ swz));    \
      const bf16x8 pf1 = *(const bf16x8*)((pw) + m * 2048 +                    \
                                          ((rl * 128 + 64 + kg * 16) ^ swz));  \
      __builtin_amdgcn_s_setprio(1);                                           \
      _Pragma("unroll") for (int dt = 0; dt < 4; ++dt) {                       \
        ot[m][dt] = mfma16(vfr[dt][0], pf0, ot[m][dt]);                        \
        ot[m][dt] = mfma16(vfr[dt][1], pf1, ot[m][dt]);                        \
      }                                                                        \
      __builtin_amdgcn_s_setprio(0);                                           \
    }                                                                          \
  }

  LOADK(ka, kvb);
  int kv = kvb;
  for (;;) {
    if (kv + 1 < kve) LOADK(kb, kv + 1);
    BODY(ka, kv, plw);
    ++kv;
    if (kv >= kve) break;
    if (kv + 1 < kve) LOADK(ka, kv + 1);
    BODY(kb, kv, plw + 4096);
    ++kv;
    if (kv >= kve) break;
  }
#undef LOADK
#undef BODY
}

__global__ __launch_bounds__(128)
void attn_kernel(const u16* __restrict__ qg, const u16* __restrict__ kgl,
                 const u16* __restrict__ vtg, u16* __restrict__ og) {
  const int tid = threadIdx.x, lane = tid & 63, wid = tid >> 6;
  const int rl = lane & 15, kg = lane >> 4;
  const int flat = blockIdx.x;
  const int bh = (flat & 7) * 4 + ((flat >> 3) & 3);
  const int pr = flat >> 5;                       // pair index 0..31
  const int jA = pr, jB = 63 - pr;                // 32-row q-subtiles
  const int nA = (jA >> 1) + 1, nB = (jB >> 1) + 1;
  const int a = (nB - nA) >> 1;                   // wave0's share of B
  const size_t rowb = (size_t)(bh >> 4) * 2048;
  const int cb = (bh & 15) * 64;
  const u16* vtb = vtg + (size_t)bh * 64 * 2048;

  __shared__ __align__(16) char Pl[2][2][4096];       // [wave][parity]
  __shared__ __align__(16) float MrgO[2][4][64][4];   // [m][dt][lane][r]
  __shared__ float MrgL[2][16];
  char* plw = Pl[wid][0];

  f32x4 ot[2][4];
  float lrun[2] = {0.f, 0.f};
#pragma unroll
  for (int m = 0; m < 2; ++m)
#pragma unroll
    for (int dt = 0; dt < 4; ++dt) ot[m][dt] = (f32x4){0.f, 0.f, 0.f, 0.f};

  if (wid == 0) {
    // subtile A complete
    attn_range(qg, kgl, vtb, rowb, cb, plw, rl, kg, jA * 32, 0, nA, true,
               ot, lrun);
#pragma unroll
    for (int m = 0; m < 2; ++m) {
      lrun[m] += __shfl_xor(lrun[m], 16);
      lrun[m] += __shfl_xor(lrun[m], 32);
      const float inv = 1.f / lrun[m];
      u16* orow = og + (rowb + jA * 32 + m * 16 + rl) * 1024 + cb;
#pragma unroll
      for (int dt = 0; dt < 4; ++dt) {
        ushort4 ok = {f2bf(ot[m][dt][0] * inv), f2bf(ot[m][dt][1] * inv),
                      f2bf(ot[m][dt][2] * inv), f2bf(ot[m][dt][3] * inv)};
        *(ushort4*)(orow + dt * 16 + 4 * kg) = ok;
      }
      lrun[m] = 0.f;
#pragma unroll
      for (int dt = 0; dt < 4; ++dt) ot[m][dt] = (f32x4){0.f, 0.f, 0.f, 0.f};
    }
    // subtile B head [0, a)
    attn_range(qg, kgl, vtb, rowb, cb, plw, rl, kg, jB * 32, 0, a, false,
               ot, lrun);
  } else {
    // subtile B tail [a, nB) incl. diagonal
    attn_range(qg, kgl, vtb, rowb, cb, plw, rl, kg, jB * 32, a, nB, true,
               ot, lrun);
#pragma unroll
    for (int m = 0; m < 2; ++m) {
      lrun[m] += __shfl_xor(lrun[m], 16);
      lrun[m] += __shfl_xor(lrun[m], 32);
#pragma unroll
      for (int dt = 0; dt < 4; ++dt)
        *(f32x4*)(&MrgO[m][dt][lane][0]) = ot[m][dt];
      if (kg == 0) MrgL[m][rl] = lrun[m];
    }
  }
  __syncthreads();
  if (wid == 0) {
#pragma unroll
    for (int m = 0; m < 2; ++m) {
      lrun[m] += __shfl_xor(lrun[m], 16);
      lrun[m] += __shfl_xor(lrun[m], 32);
      const float inv = 1.f / (lrun[m] + MrgL[m][rl]);
      u16* orow = og + (rowb + jB * 32 + m * 16 + rl) * 1024 + cb;
#pragma unroll
      for (int dt = 0; dt < 4; ++dt) {
        const f32x4 o1 = *(const f32x4*)(&MrgO[m][dt][lane][0]);
        ushort4 ok;
#pragma unroll
        for (int r = 0; r < 4; ++r)
          ((u16*)&ok)[r] = f2bf((ot[m][dt][r] + o1[r]) * inv);
        *(ushort4*)(orow + dt * 16 + 4 * kg) = ok;
      }
    }
  }
}

// ---------------- launch ----------------

extern "C" void kernel_launch(void* const* d_in, const int* in_sizes, int n_in,
                              void* d_out, int out_size, void* d_ws, size_t ws_size,
                              hipStream_t stream) {
  const float* x    = (const float*)d_in[0];
  const float* Wq   = (const float*)d_in[1];
  const float* Wk   = (const float*)d_in[2];
  const float* Wv   = (const float*)d_in[3];
  const float* Wo   = (const float*)d_in[4];
  const float* bo   = (const float*)d_in[5];
  const float* W1   = (const float*)d_in[6];
  const float* b1   = (const float*)d_in[7];
  const float* W2   = (const float*)d_in[8];
  const float* b2   = (const float*)d_in[9];
  const float* ln1g = (const float*)d_in[10];
  const float* ln1b = (const float*)d_in[11];
  const float* ln2g = (const float*)d_in[12];
  const float* ln2b = (const float*)d_in[13];
  float* out = (float*)d_out;

  char* ws = (char*)d_ws;
  const size_t MB = 1024 * 1024;
  u16* WqT  = (u16*)(ws + 0 * MB);    // [3072][1024] contiguous (Wq,Wk,Wv)
  u16* WoT  = (u16*)(ws + 6 * MB);
  u16* W1T  = (u16*)(ws + 8 * MB);
  u16* W2T  = (u16*)(ws + 16 * MB);
  u16* h    = (u16*)(ws + 24 * MB);
  u16* q    = (u16*)(ws + 32 * MB);
  u16* k    = (u16*)(ws + 40 * MB);
  u16* vt   = (u16*)(ws + 48 * MB);   // [32][64][2048] bf16
  u16* attn = (u16*)(ws + 56 * MB);
  u16* x1b  = (u16*)(ws + 64 * MB);   // [4096][1024] bf16
  u16* ff1  = (u16*)(ws + 32 * MB);   // aliases q/k/vt/attn
  u16* WkT  = WqT + 1024 * 1024;
  u16* WvT  = WqT + 2 * 1024 * 1024;

  // transposes + ln1 fused
  prep_kernel<<<16384, 256, 0, stream>>>(Wq, Wk, Wv, Wo, W1, W2,
                                         WqT, WkT, WvT, WoT, W1T, W2T,
                                         x, ln1g, ln1b, h);

  // QKV fused: Bt = [WqT;WkT;WvT] (3072x1024); writes q, k, vt
  gemm256<0><<<dim3(24, 16), 512, 0, stream>>>(h, WqT, nullptr,
                                               q, k, vt, 4096, 3072, 1024);

  attn_kernel<<<1024, 128, 0, stream>>>(q, k, vt, attn);

  // x1 (bf16) = x + attn @ Wo + bo
  gemm64<0><<<dim3(8, 64), 256, 0, stream>>>(attn, WoT, bo, x, x1b,
                                             4096, 1024, 1024);

  ln_kernel<<<4096, 256, 0, stream>>>(x1b, ln2g, ln2b, h);

  // ff1 = relu(h2 @ W1 + b1)
  gemm256<1><<<dim3(32, 16), 512, 0, stream>>>(h, W1T, b1, ff1, ff1, ff1,
                                               4096, 4096, 1024);

  // out (f32) = x1 + ff1 @ W2 + b2
  gemm64<1><<<dim3(8, 64), 256, 0, stream>>>(ff1, W2T, b2, x1b, out,
                                             4096, 1024, 4096);
}